// Round 1
// baseline (973.202 us; speedup 1.0000x reference)
//
#include <hip/hip_runtime.h>
#include <cstddef>

static constexpr int NN = 100000;   // nodes
static constexpr int NE = 1600000;  // edges
static constexpr int D  = 64;
static constexpr int H  = 128;
static constexpr int O  = 64;
static constexpr int TILE = 1024;
static constexpr int NT = (NN + TILE - 1) / TILE;   // 98 scan tiles

// ---------------- CSR construction ----------------

__global__ void zero_i32(int* p, int n) {
    int i = blockIdx.x * blockDim.x + threadIdx.x;
    if (i < n) p[i] = 0;
}

// edge_index layout: src = eidx[0..NE), dst = eidx[NE..2NE)  (int32 per harness)
__global__ void hist_kernel(const int* __restrict__ eidx, int* __restrict__ counts) {
    int e = blockIdx.x * blockDim.x + threadIdx.x;
    if (e < NE) atomicAdd(&counts[eidx[NE + e]], 1);
}

__global__ void scan_phaseA(const int* __restrict__ counts, int* __restrict__ bsum) {
    __shared__ int s[256];
    int t = threadIdx.x, b = blockIdx.x;
    int base = b * TILE + t * 4;
    int acc = 0;
#pragma unroll
    for (int j = 0; j < 4; j++) { int i = base + j; if (i < NN) acc += counts[i]; }
    s[t] = acc; __syncthreads();
    for (int off = 128; off > 0; off >>= 1) {
        if (t < off) s[t] += s[t + off];
        __syncthreads();
    }
    if (t == 0) bsum[b] = s[0];
}

__global__ void scan_phaseB(const int* __restrict__ bsum, int* __restrict__ boff,
                            int* __restrict__ row_ptr) {
    __shared__ int s[128];
    int t = threadIdx.x;
    int v = (t < NT) ? bsum[t] : 0;
    s[t] = v; __syncthreads();
    for (int off = 1; off < 128; off <<= 1) {
        int x = (t >= off) ? s[t - off] : 0;
        __syncthreads();
        s[t] += x;
        __syncthreads();
    }
    boff[t] = s[t] - v;                 // exclusive
    if (t == 127) row_ptr[NN] = s[127]; // total == NE
}

__global__ void scan_phaseC(const int* __restrict__ counts, const int* __restrict__ boff,
                            int* __restrict__ row_ptr, int* __restrict__ cursor) {
    __shared__ int s[256];
    int t = threadIdx.x, b = blockIdx.x;
    int base = b * TILE + t * 4;
    int v[4];
#pragma unroll
    for (int j = 0; j < 4; j++) { int i = base + j; v[j] = (i < NN) ? counts[i] : 0; }
    int tsum = v[0] + v[1] + v[2] + v[3];
    s[t] = tsum; __syncthreads();
    for (int off = 1; off < 256; off <<= 1) {
        int x = (t >= off) ? s[t - off] : 0;
        __syncthreads();
        s[t] += x;
        __syncthreads();
    }
    int pre = boff[b] + s[t] - tsum;    // exclusive prefix for this thread's first elem
#pragma unroll
    for (int j = 0; j < 4; j++) {
        int i = base + j;
        if (i < NN) { row_ptr[i] = pre; cursor[i] = pre; }
        pre += v[j];
    }
}

__global__ void fill_kernel(const int* __restrict__ eidx, int* __restrict__ cursor,
                            int* __restrict__ ecsr) {
    int e = blockIdx.x * blockDim.x + threadIdx.x;
    if (e < NE) {
        int d = eidx[NE + e];
        int pos = atomicAdd(&cursor[d], 1);
        ecsr[pos] = eidx[e];   // store src
    }
}

// ---------------- mean aggregation (gather via CSR) ----------------
// F threads per node, lane = feature index; contiguous 4B*F row reads.
template<int F>
__global__ void aggregate_kernel(const float* __restrict__ feat, const int* __restrict__ row_ptr,
                                 const int* __restrict__ ecsr, float* __restrict__ meanout) {
    constexpr int NPB = 256 / F;
    int node = blockIdx.x * NPB + threadIdx.x / F;
    int lane = threadIdx.x % F;
    if (node >= NN) return;
    int beg = row_ptr[node], end = row_ptr[node + 1];
    float s = 0.f;
    for (int i = beg; i < end; i++) {
        int sn = ecsr[i];
        s += feat[(size_t)sn * F + lane];
    }
    int deg = end - beg;
    meanout[(size_t)node * F + lane] = (deg > 0) ? s / (float)deg : 0.f;
}

// ---------------- fused fp32 GEMM:  out = [relu]( A1@W1 [+ A2@W2] + bias ) ----------------
// A: [NN x K] row-major, W: [K x C] row-major, out: [NN x C].
// 64 rows per block, A tiles in LDS (pad +4 floats -> free 2-way bank aliasing only),
// weights streamed via coalesced float4 (L1/L2 resident: <=64KB per matrix).
template<int K, int C, bool DUAL, bool RELU>
__launch_bounds__(256)
__global__ void gemm_fused(const float* __restrict__ A1, const float* __restrict__ W1,
                           const float* __restrict__ A2, const float* __restrict__ W2,
                           const float* __restrict__ bias, float* __restrict__ out) {
    constexpr int TM  = 64;
    constexpr int KP  = K + 4;          // padded LDS row stride (keeps 16B align)
    constexpr int CG  = C / 4;          // col groups (float4 per thread)
    constexpr int RG  = 256 / CG;       // row-thread groups
    constexpr int RPT = TM / RG;        // rows per thread
    __shared__ float As1[TM * KP];
    __shared__ float As2[DUAL ? TM * KP : 4];

    const int tid  = threadIdx.x;
    const int row0 = blockIdx.x * TM;

    constexpr int NV = TM * K / 4;      // float4 count of one A tile
    for (int v = tid; v < NV; v += 256) {
        int e = v * 4; int r = e / K; int k = e % K;
        int gr = row0 + r;
        float4 a = (gr < NN) ? *(const float4*)&A1[(size_t)gr * K + k]
                             : make_float4(0.f, 0.f, 0.f, 0.f);
        *(float4*)&As1[r * KP + k] = a;
        if constexpr (DUAL) {
            float4 a2 = (gr < NN) ? *(const float4*)&A2[(size_t)gr * K + k]
                                  : make_float4(0.f, 0.f, 0.f, 0.f);
            *(float4*)&As2[r * KP + k] = a2;
        }
    }
    __syncthreads();

    const int tx = tid % CG, ty = tid / CG;
    const int c0 = tx * 4;
    const int rbase = ty * RPT;

    float acc[RPT][4];
    {
        float4 b4 = *(const float4*)&bias[c0];
#pragma unroll
        for (int i = 0; i < RPT; i++) {
            acc[i][0] = b4.x; acc[i][1] = b4.y; acc[i][2] = b4.z; acc[i][3] = b4.w;
        }
    }

    for (int k = 0; k < K; k += 4) {
        float w1[4][4];
#pragma unroll
        for (int kk = 0; kk < 4; kk++) {
            float4 t = *(const float4*)&W1[(size_t)(k + kk) * C + c0];
            w1[kk][0] = t.x; w1[kk][1] = t.y; w1[kk][2] = t.z; w1[kk][3] = t.w;
        }
#pragma unroll
        for (int i = 0; i < RPT; i++) {
            float4 a = *(const float4*)&As1[(rbase + i) * KP + k];
#pragma unroll
            for (int j = 0; j < 4; j++)
                acc[i][j] += a.x * w1[0][j] + a.y * w1[1][j] + a.z * w1[2][j] + a.w * w1[3][j];
        }
        if constexpr (DUAL) {
            float w2[4][4];
#pragma unroll
            for (int kk = 0; kk < 4; kk++) {
                float4 t = *(const float4*)&W2[(size_t)(k + kk) * C + c0];
                w2[kk][0] = t.x; w2[kk][1] = t.y; w2[kk][2] = t.z; w2[kk][3] = t.w;
            }
#pragma unroll
            for (int i = 0; i < RPT; i++) {
                float4 a = *(const float4*)&As2[(rbase + i) * KP + k];
#pragma unroll
                for (int j = 0; j < 4; j++)
                    acc[i][j] += a.x * w2[0][j] + a.y * w2[1][j] + a.z * w2[2][j] + a.w * w2[3][j];
            }
        }
    }

#pragma unroll
    for (int i = 0; i < RPT; i++) {
        int gr = row0 + rbase + i;
        if (gr < NN) {
            float4 o;
            o.x = RELU ? fmaxf(acc[i][0], 0.f) : acc[i][0];
            o.y = RELU ? fmaxf(acc[i][1], 0.f) : acc[i][1];
            o.z = RELU ? fmaxf(acc[i][2], 0.f) : acc[i][2];
            o.w = RELU ? fmaxf(acc[i][3], 0.f) : acc[i][3];
            *(float4*)&out[(size_t)gr * C + c0] = o;
        }
    }
}

// ---------------- launch ----------------

extern "C" void kernel_launch(void* const* d_in, const int* in_sizes, int n_in,
                              void* d_out, int out_size, void* d_ws, size_t ws_size,
                              hipStream_t stream) {
    const float* x     = (const float*)d_in[0];
    const int*   eidx  = (const int*)d_in[1];
    const float* W1l   = (const float*)d_in[2];
    const float* b1    = (const float*)d_in[3];
    const float* W1r   = (const float*)d_in[4];
    const float* Wlin1 = (const float*)d_in[5];
    const float* blin1 = (const float*)d_in[6];
    const float* W2l   = (const float*)d_in[7];
    const float* b2    = (const float*)d_in[8];
    const float* W2r   = (const float*)d_in[9];
    const float* Wlin2 = (const float*)d_in[10];
    const float* blin2 = (const float*)d_in[11];
    float* out = (float*)d_out;
    (void)in_sizes; (void)n_in; (void)out_size; (void)ws_size;

    char* ws = (char*)d_ws;
    size_t off = 0;
    auto alloc = [&](size_t bytes) -> void* {
        void* p = ws + off;
        off = (off + bytes + 255) & ~(size_t)255;
        return p;
    };
    int*   counts  = (int*)alloc((size_t)NN * 4);
    int*   bsum    = (int*)alloc(128 * 4);
    int*   boff    = (int*)alloc(128 * 4);
    int*   row_ptr = (int*)alloc((size_t)(NN + 1) * 4);
    int*   cursor  = (int*)alloc((size_t)NN * 4);
    int*   ecsr    = (int*)alloc((size_t)NE * 4);
    float* bufA    = (float*)alloc((size_t)NN * H * 4);
    float* bufB    = (float*)alloc((size_t)NN * H * 4);
    float* bufC    = (float*)alloc((size_t)NN * H * 4);

    // CSR build (reused by both layers)
    zero_i32<<<(NN + 255) / 256, 256, 0, stream>>>(counts, NN);
    hist_kernel<<<(NE + 255) / 256, 256, 0, stream>>>(eidx, counts);
    scan_phaseA<<<NT, 256, 0, stream>>>(counts, bsum);
    scan_phaseB<<<1, 128, 0, stream>>>(bsum, boff, row_ptr);
    scan_phaseC<<<NT, 256, 0, stream>>>(counts, boff, row_ptr, cursor);
    fill_kernel<<<(NE + 255) / 256, 256, 0, stream>>>(eidx, cursor, ecsr);

    const int GB = (NN + 63) / 64;  // gemm blocks

    // Layer 1: mean1 = agg(x); h1 = relu(mean1@W1l + x@W1r + b1); h = relu(h1@Wlin1 + blin1)
    aggregate_kernel<64><<<NN / 4, 256, 0, stream>>>(x, row_ptr, ecsr, bufA);
    gemm_fused<64, 128, true, true><<<GB, 256, 0, stream>>>(bufA, W1l, x, W1r, b1, bufB);
    gemm_fused<128, 128, false, true><<<GB, 256, 0, stream>>>(bufB, Wlin1, nullptr, nullptr, blin1, bufC);

    // Layer 2: mean2 = agg(h); h2 = relu(mean2@W2l + h@W2r + b2); out = h2@Wlin2 + blin2
    aggregate_kernel<128><<<NN / 2, 256, 0, stream>>>(bufC, row_ptr, ecsr, bufA);
    gemm_fused<128, 128, true, true><<<GB, 256, 0, stream>>>(bufA, W2l, bufC, W2r, b2, bufB);
    gemm_fused<128, 64, false, false><<<GB, 256, 0, stream>>>(bufB, Wlin2, nullptr, nullptr, blin2, out);
}

// Round 2
// 729.273 us; speedup vs baseline: 1.3345x; 1.3345x over previous
//
#include <hip/hip_runtime.h>
#include <cstddef>

static constexpr int NN = 100000;   // nodes
static constexpr int NE = 1600000;  // edges
static constexpr int D  = 64;
static constexpr int H  = 128;
static constexpr int O  = 64;
static constexpr int TILE = 1024;
static constexpr int NT = (NN + TILE - 1) / TILE;   // 98 scan tiles

// ---------------- CSR construction ----------------

__global__ void zero_i32(int* p, int n) {
    int i = blockIdx.x * blockDim.x + threadIdx.x;
    if (i < n) p[i] = 0;
}

// edge_index layout: src = eidx[0..NE), dst = eidx[NE..2NE)  (int32 per harness)
__global__ void hist_kernel(const int* __restrict__ eidx, int* __restrict__ counts) {
    int e = blockIdx.x * blockDim.x + threadIdx.x;
    if (e < NE) atomicAdd(&counts[eidx[NE + e]], 1);
}

__global__ void scan_phaseA(const int* __restrict__ counts, int* __restrict__ bsum) {
    __shared__ int s[256];
    int t = threadIdx.x, b = blockIdx.x;
    int base = b * TILE + t * 4;
    int acc = 0;
#pragma unroll
    for (int j = 0; j < 4; j++) { int i = base + j; if (i < NN) acc += counts[i]; }
    s[t] = acc; __syncthreads();
    for (int off = 128; off > 0; off >>= 1) {
        if (t < off) s[t] += s[t + off];
        __syncthreads();
    }
    if (t == 0) bsum[b] = s[0];
}

__global__ void scan_phaseB(const int* __restrict__ bsum, int* __restrict__ boff,
                            int* __restrict__ row_ptr) {
    __shared__ int s[128];
    int t = threadIdx.x;
    int v = (t < NT) ? bsum[t] : 0;
    s[t] = v; __syncthreads();
    for (int off = 1; off < 128; off <<= 1) {
        int x = (t >= off) ? s[t - off] : 0;
        __syncthreads();
        s[t] += x;
        __syncthreads();
    }
    boff[t] = s[t] - v;                 // exclusive
    if (t == 127) row_ptr[NN] = s[127]; // total == NE
}

__global__ void scan_phaseC(const int* __restrict__ counts, const int* __restrict__ boff,
                            int* __restrict__ row_ptr, int* __restrict__ cursor) {
    __shared__ int s[256];
    int t = threadIdx.x, b = blockIdx.x;
    int base = b * TILE + t * 4;
    int v[4];
#pragma unroll
    for (int j = 0; j < 4; j++) { int i = base + j; v[j] = (i < NN) ? counts[i] : 0; }
    int tsum = v[0] + v[1] + v[2] + v[3];
    s[t] = tsum; __syncthreads();
    for (int off = 1; off < 256; off <<= 1) {
        int x = (t >= off) ? s[t - off] : 0;
        __syncthreads();
        s[t] += x;
        __syncthreads();
    }
    int pre = boff[b] + s[t] - tsum;    // exclusive prefix for this thread's first elem
#pragma unroll
    for (int j = 0; j < 4; j++) {
        int i = base + j;
        if (i < NN) { row_ptr[i] = pre; cursor[i] = pre; }
        pre += v[j];
    }
}

__global__ void fill_kernel(const int* __restrict__ eidx, int* __restrict__ cursor,
                            int* __restrict__ ecsr) {
    int e = blockIdx.x * blockDim.x + threadIdx.x;
    if (e < NE) {
        int d = eidx[NE + e];
        int pos = atomicAdd(&cursor[d], 1);
        ecsr[pos] = eidx[e];   // store src
    }
}

// ---------------- mean aggregation (gather via CSR) ----------------
// float4 per lane: F/4 threads per node. Edge loop unrolled x4 with independent
// accumulators -> 4 outstanding 16B gathers per lane (latency -> BW bound).
template<int F>
__launch_bounds__(256)
__global__ void aggregate_kernel(const float* __restrict__ feat, const int* __restrict__ row_ptr,
                                 const int* __restrict__ ecsr, float* __restrict__ meanout) {
    constexpr int TPN = F / 4;        // threads per node
    constexpr int NPB = 256 / TPN;    // nodes per block
    int node = blockIdx.x * NPB + threadIdx.x / TPN;
    int lane = threadIdx.x % TPN;
    if (node >= NN) return;
    int beg = row_ptr[node], end = row_ptr[node + 1];
    const float4* frow = (const float4*)feat;

    float4 a0 = make_float4(0.f, 0.f, 0.f, 0.f);
    float4 a1 = a0, a2 = a0, a3 = a0;

    int i = beg;
    for (; i + 4 <= end; i += 4) {
        int s0 = ecsr[i + 0], s1 = ecsr[i + 1], s2 = ecsr[i + 2], s3 = ecsr[i + 3];
        float4 v0 = frow[(size_t)s0 * TPN + lane];
        float4 v1 = frow[(size_t)s1 * TPN + lane];
        float4 v2 = frow[(size_t)s2 * TPN + lane];
        float4 v3 = frow[(size_t)s3 * TPN + lane];
        a0.x += v0.x; a0.y += v0.y; a0.z += v0.z; a0.w += v0.w;
        a1.x += v1.x; a1.y += v1.y; a1.z += v1.z; a1.w += v1.w;
        a2.x += v2.x; a2.y += v2.y; a2.z += v2.z; a2.w += v2.w;
        a3.x += v3.x; a3.y += v3.y; a3.z += v3.z; a3.w += v3.w;
    }
    for (; i < end; i++) {
        int s0 = ecsr[i];
        float4 v0 = frow[(size_t)s0 * TPN + lane];
        a0.x += v0.x; a0.y += v0.y; a0.z += v0.z; a0.w += v0.w;
    }
    a0.x += a1.x + a2.x + a3.x;
    a0.y += a1.y + a2.y + a3.y;
    a0.z += a1.z + a2.z + a3.z;
    a0.w += a1.w + a2.w + a3.w;

    int deg = end - beg;
    float r = (deg > 0) ? 1.f / (float)deg : 0.f;
    float4 o = make_float4(a0.x * r, a0.y * r, a0.z * r, a0.w * r);
    ((float4*)meanout)[(size_t)node * TPN + lane] = o;
}

// ---------------- fused fp32 GEMM:  out = [relu]( A1@W1 [+ A2@W2] + bias ) ----------------
// A: [NN x K] row-major, W: [K x C] row-major, out: [NN x C].
template<int K, int C, bool DUAL, bool RELU>
__launch_bounds__(256)
__global__ void gemm_fused(const float* __restrict__ A1, const float* __restrict__ W1,
                           const float* __restrict__ A2, const float* __restrict__ W2,
                           const float* __restrict__ bias, float* __restrict__ out) {
    constexpr int TM  = 64;
    constexpr int KP  = K + 4;          // padded LDS row stride (keeps 16B align)
    constexpr int CG  = C / 4;          // col groups (float4 per thread)
    constexpr int RG  = 256 / CG;       // row-thread groups
    constexpr int RPT = TM / RG;        // rows per thread
    __shared__ float As1[TM * KP];
    __shared__ float As2[DUAL ? TM * KP : 4];

    const int tid  = threadIdx.x;
    const int row0 = blockIdx.x * TM;

    constexpr int NV = TM * K / 4;      // float4 count of one A tile
    for (int v = tid; v < NV; v += 256) {
        int e = v * 4; int r = e / K; int k = e % K;
        int gr = row0 + r;
        float4 a = (gr < NN) ? *(const float4*)&A1[(size_t)gr * K + k]
                             : make_float4(0.f, 0.f, 0.f, 0.f);
        *(float4*)&As1[r * KP + k] = a;
        if constexpr (DUAL) {
            float4 a2 = (gr < NN) ? *(const float4*)&A2[(size_t)gr * K + k]
                                  : make_float4(0.f, 0.f, 0.f, 0.f);
            *(float4*)&As2[r * KP + k] = a2;
        }
    }
    __syncthreads();

    const int tx = tid % CG, ty = tid / CG;
    const int c0 = tx * 4;
    const int rbase = ty * RPT;

    float acc[RPT][4];
    {
        float4 b4 = *(const float4*)&bias[c0];
#pragma unroll
        for (int i = 0; i < RPT; i++) {
            acc[i][0] = b4.x; acc[i][1] = b4.y; acc[i][2] = b4.z; acc[i][3] = b4.w;
        }
    }

    for (int k = 0; k < K; k += 4) {
        float w1[4][4];
#pragma unroll
        for (int kk = 0; kk < 4; kk++) {
            float4 t = *(const float4*)&W1[(size_t)(k + kk) * C + c0];
            w1[kk][0] = t.x; w1[kk][1] = t.y; w1[kk][2] = t.z; w1[kk][3] = t.w;
        }
#pragma unroll
        for (int i = 0; i < RPT; i++) {
            float4 a = *(const float4*)&As1[(rbase + i) * KP + k];
#pragma unroll
            for (int j = 0; j < 4; j++)
                acc[i][j] += a.x * w1[0][j] + a.y * w1[1][j] + a.z * w1[2][j] + a.w * w1[3][j];
        }
        if constexpr (DUAL) {
            float w2[4][4];
#pragma unroll
            for (int kk = 0; kk < 4; kk++) {
                float4 t = *(const float4*)&W2[(size_t)(k + kk) * C + c0];
                w2[kk][0] = t.x; w2[kk][1] = t.y; w2[kk][2] = t.z; w2[kk][3] = t.w;
            }
#pragma unroll
            for (int i = 0; i < RPT; i++) {
                float4 a = *(const float4*)&As2[(rbase + i) * KP + k];
#pragma unroll
                for (int j = 0; j < 4; j++)
                    acc[i][j] += a.x * w2[0][j] + a.y * w2[1][j] + a.z * w2[2][j] + a.w * w2[3][j];
            }
        }
    }

#pragma unroll
    for (int i = 0; i < RPT; i++) {
        int gr = row0 + rbase + i;
        if (gr < NN) {
            float4 o;
            o.x = RELU ? fmaxf(acc[i][0], 0.f) : acc[i][0];
            o.y = RELU ? fmaxf(acc[i][1], 0.f) : acc[i][1];
            o.z = RELU ? fmaxf(acc[i][2], 0.f) : acc[i][2];
            o.w = RELU ? fmaxf(acc[i][3], 0.f) : acc[i][3];
            *(float4*)&out[(size_t)gr * C + c0] = o;
        }
    }
}

// ---------------- launch ----------------

extern "C" void kernel_launch(void* const* d_in, const int* in_sizes, int n_in,
                              void* d_out, int out_size, void* d_ws, size_t ws_size,
                              hipStream_t stream) {
    const float* x     = (const float*)d_in[0];
    const int*   eidx  = (const int*)d_in[1];
    const float* W1l   = (const float*)d_in[2];
    const float* b1    = (const float*)d_in[3];
    const float* W1r   = (const float*)d_in[4];
    const float* Wlin1 = (const float*)d_in[5];
    const float* blin1 = (const float*)d_in[6];
    const float* W2l   = (const float*)d_in[7];
    const float* b2    = (const float*)d_in[8];
    const float* W2r   = (const float*)d_in[9];
    const float* Wlin2 = (const float*)d_in[10];
    const float* blin2 = (const float*)d_in[11];
    float* out = (float*)d_out;
    (void)in_sizes; (void)n_in; (void)out_size; (void)ws_size;

    char* ws = (char*)d_ws;
    size_t off = 0;
    auto alloc = [&](size_t bytes) -> void* {
        void* p = ws + off;
        off = (off + bytes + 255) & ~(size_t)255;
        return p;
    };
    int*   counts  = (int*)alloc((size_t)NN * 4);
    int*   bsum    = (int*)alloc(128 * 4);
    int*   boff    = (int*)alloc(128 * 4);
    int*   row_ptr = (int*)alloc((size_t)(NN + 1) * 4);
    int*   cursor  = (int*)alloc((size_t)NN * 4);
    int*   ecsr    = (int*)alloc((size_t)NE * 4);
    float* bufA    = (float*)alloc((size_t)NN * H * 4);
    float* bufB    = (float*)alloc((size_t)NN * H * 4);
    float* bufC    = (float*)alloc((size_t)NN * H * 4);

    // CSR build (reused by both layers)
    zero_i32<<<(NN + 255) / 256, 256, 0, stream>>>(counts, NN);
    hist_kernel<<<(NE + 255) / 256, 256, 0, stream>>>(eidx, counts);
    scan_phaseA<<<NT, 256, 0, stream>>>(counts, bsum);
    scan_phaseB<<<1, 128, 0, stream>>>(bsum, boff, row_ptr);
    scan_phaseC<<<NT, 256, 0, stream>>>(counts, boff, row_ptr, cursor);
    fill_kernel<<<(NE + 255) / 256, 256, 0, stream>>>(eidx, cursor, ecsr);

    const int GB = (NN + 63) / 64;  // gemm blocks

    // Layer 1: mean1 = agg(x); h1 = relu(mean1@W1l + x@W1r + b1); h = relu(h1@Wlin1 + blin1)
    aggregate_kernel<64><<<(NN + 15) / 16, 256, 0, stream>>>(x, row_ptr, ecsr, bufA);
    gemm_fused<64, 128, true, true><<<GB, 256, 0, stream>>>(bufA, W1l, x, W1r, b1, bufB);
    gemm_fused<128, 128, false, true><<<GB, 256, 0, stream>>>(bufB, Wlin1, nullptr, nullptr, blin1, bufC);

    // Layer 2: mean2 = agg(h); h2 = relu(mean2@W2l + h@W2r + b2); out = h2@Wlin2 + blin2
    aggregate_kernel<128><<<(NN + 7) / 8, 256, 0, stream>>>(bufC, row_ptr, ecsr, bufA);
    gemm_fused<128, 128, true, true><<<GB, 256, 0, stream>>>(bufA, W2l, bufC, W2r, b2, bufB);
    gemm_fused<128, 64, false, false><<<GB, 256, 0, stream>>>(bufB, Wlin2, nullptr, nullptr, blin2, out);
}